// Round 6
// baseline (203.602 us; speedup 1.0000x reference)
//
#include <hip/hip_runtime.h>

// SimpleUnsharedPatchScorer — scatter formulation.
// scores[b,pout] = sum over t in [pout*768,(pout+1)*768) of x[b, c,16h+i,16w+j] * wflat[t] + bias[pout]
//   where t = i*9408 + j*588 + c*196 + h*14 + w  (digits i,j in [0,16), c in [0,3), h,w in [0,14)).
// Inverse (per x element m = c*50176 + H*224 + W): h=H>>4, i=H&15, w=W>>4, j=W&15 -> t(m).
// Round-5 rocprof: gather kernel was latency-bound (1.8 TB/s, 127us, 222MB fetch).
// Fix: read x/Wperm/pidx fully coalesced; scatter into per-wave LDS bins via ds_add_f32.

#define NELEM  150528          // 3*224*224 elements per image
#define NF4    37632           // NELEM/4
#define CHUNK  4704            // NF4/8 float4s per block
#define NPATCH 196
#define NB     256
#define IMG2   50176           // 224*224

// ws layout: [0,602112) Wperm f32[150528]; [602112,903168) pidx u16[150528]

__global__ __launch_bounds__(256) void prep_kernel(
    const float* __restrict__ weight,   // [196*768] flat
    const float* __restrict__ bias,     // [196]
    float* __restrict__ wperm,          // ws
    unsigned short* __restrict__ pidx,  // ws
    float* __restrict__ out)            // [256,196] -> init with bias
{
    const int bid = blockIdx.x;
    if (bid < 588) {                    // 588*256 == 150528
        const int m = bid * 256 + threadIdx.x;
        const int c   = m / IMG2;
        const int rem = m - c * IMG2;
        const int H   = rem / 224;
        const int W   = rem - H * 224;
        const int h = H >> 4, i = H & 15;
        const int w = W >> 4, j = W & 15;
        const int t = i * 9408 + j * 588 + c * 196 + h * 14 + w;
        wperm[m] = weight[t];
        pidx[m]  = (unsigned short)(t / 768);
    } else {                            // 196*256 == 50176 bias-init threads
        const int g = (bid - 588) * 256 + threadIdx.x;
        if (g < NB * NPATCH) out[g] = bias[g % NPATCH];
    }
}

__global__ __launch_bounds__(256) void scatter_kernel(
    const float* __restrict__ x,             // [256,3,224,224]
    const float* __restrict__ wperm,
    const unsigned short* __restrict__ pidx,
    float* __restrict__ out)                 // [256,196] (bias pre-loaded)
{
    __shared__ float bins[4 * NPATCH];       // per-wave bin arrays
    const int tid = threadIdx.x;
    for (int k = tid; k < 4 * NPATCH; k += 256) bins[k] = 0.0f;
    __syncthreads();

    const int bid = blockIdx.x;
    const int b   = bid >> 3;                // image
    const int q   = bid & 7;                 // chunk; dispatch round-robin -> XCD==q shares Wperm slice
    const float4*  __restrict__ x4 = (const float4*)(x + (size_t)b * NELEM);
    const float4*  __restrict__ w4 = (const float4*)wperm;
    const ushort4* __restrict__ p4 = (const ushort4*)pidx;
    float* mybins = bins + (tid >> 6) * NPATCH;

    const int end = (q + 1) * CHUNK;
    for (int i4 = q * CHUNK + tid; i4 < end; i4 += 256) {
        const float4  xv = x4[i4];
        const float4  wv = w4[i4];
        const ushort4 pv = p4[i4];
        unsafeAtomicAdd(&mybins[pv.x], xv.x * wv.x);  // ds_add_f32
        unsafeAtomicAdd(&mybins[pv.y], xv.y * wv.y);
        unsafeAtomicAdd(&mybins[pv.z], xv.z * wv.z);
        unsafeAtomicAdd(&mybins[pv.w], xv.w * wv.w);
    }
    __syncthreads();

    for (int p = tid; p < NPATCH; p += 256) {
        const float s = bins[p] + bins[NPATCH + p] + bins[2 * NPATCH + p] + bins[3 * NPATCH + p];
        unsafeAtomicAdd(&out[b * NPATCH + p], s);     // global_atomic_add_f32, device scope
    }
}

extern "C" void kernel_launch(void* const* d_in, const int* in_sizes, int n_in,
                              void* d_out, int out_size, void* d_ws, size_t ws_size,
                              hipStream_t stream) {
    const float* x      = (const float*)d_in[0];
    const float* weight = (const float*)d_in[1];
    const float* bias   = (const float*)d_in[2];
    float* out          = (float*)d_out;

    float*          wperm = (float*)d_ws;                       // 602112 B
    unsigned short* pidx  = (unsigned short*)((char*)d_ws + 602112); // 301056 B

    prep_kernel<<<784, 256, 0, stream>>>(weight, bias, wperm, pidx, out);
    scatter_kernel<<<NB * 8, 256, 0, stream>>>(x, wperm, pidx, out);
}

// Round 7
// 61.489 us; speedup vs baseline: 3.3112x; 3.3112x over previous
//
#include <hip/hip_runtime.h>

// SimpleUnsharedPatchScorer — register-run reduction.
// t = i*9408 + j*588 + c*196 + h*14 + w  (i,j in [0,16), c in [0,3), h,w in [0,14))
// value at t: x[b, c, 16h+i, 16w+j];  out bin p = t/768.
// Per (c,h) tile: one wave, lane=(i,j4), dj in [0,4): 14-step w-loop, coalesced float4
// x + permuted-weight loads, per-run register accumulation, ~1 global atomic per run.
// Round-6 lesson: per-element LDS atomics = serialization wall (VALUBusy 2.3%). Avoid.

#define NPATCH 196
#define NF4IMG 37632     // floats4 per image = 150528/4

// prep: wlay[((c*14+h)*14+w)*256 + i*16 + j] = weight[i*9408 + j*588 + c*196 + h*14 + w]
__global__ __launch_bounds__(256) void prep_kernel(
    const float* __restrict__ weight,
    const float* __restrict__ bias,
    float* __restrict__ wlay,
    float* __restrict__ out)
{
    const int bid = blockIdx.x;
    if (bid < 588) {                         // 588*256 == 150528
        const int f = bid * 256 + threadIdx.x;
        const int j    = f & 15;
        const int i    = (f >> 4) & 15;
        const int rest = f >> 8;             // (c*14+h)*14 + w, < 588
        const int w  = rest % 14;
        const int ch = rest / 14;
        const int h  = ch % 14;
        const int c  = ch / 14;
        wlay[f] = weight[i * 9408 + j * 588 + c * 196 + h * 14 + w];
    } else {                                 // bias-init out: 196*256 == 50176
        const int g = (bid - 588) * 256 + threadIdx.x;
        if (g < 256 * NPATCH) out[g] = bias[g % NPATCH];
    }
}

__global__ __launch_bounds__(256) void run_kernel(
    const float* __restrict__ x,     // [256,3,224,224]
    const float* __restrict__ wlay,  // permuted weights
    float* __restrict__ out)         // [256,196], bias pre-loaded
{
    const int wv   = blockIdx.x * 4 + (threadIdx.x >> 6);  // global wave id < 10752
    const int lane = threadIdx.x & 63;
    const int b    = wv / 42;
    const int tile = wv - b * 42;            // c*14 + h
    const int c    = tile / 14;
    const int h    = tile - c * 14;
    const int i    = lane >> 2;
    const int j4   = lane & 3;               // j = 4*j4 + dj

    const float4* __restrict__ x4 = (const float4*)x + (size_t)b * NF4IMG
                                    + c * 12544 + (16 * h + i) * 56 + j4;
    const float4* __restrict__ w4 = (const float4*)wlay + tile * (14 * 64) + i * 4 + j4;

    // per-dj run metadata: bin p0 and split point ws (w >= ws goes to bin p0+1)
    int p0[4], ws[4];
    #pragma unroll
    for (int dj = 0; dj < 4; ++dj) {
        const int jj = 4 * j4 + dj;
        const int t0 = i * 9408 + jj * 588 + c * 196 + h * 14;
        p0[dj] = t0 / 768;
        ws[dj] = 768 * (p0[dj] + 1) - t0;    // >= 1; >= 14 means no split
    }

    float accA[4] = {0.f, 0.f, 0.f, 0.f};    // w <  ws  -> bin p0
    float accB[4] = {0.f, 0.f, 0.f, 0.f};    // w >= ws  -> bin p0+1

    #pragma unroll
    for (int w = 0; w < 14; ++w) {
        const float4 xv = x4[4 * w];
        const float4 wv_ = w4[64 * w];
        const float xs[4] = {xv.x, xv.y, xv.z, xv.w};
        const float wsv[4] = {wv_.x, wv_.y, wv_.z, wv_.w};
        #pragma unroll
        for (int dj = 0; dj < 4; ++dj) {
            const float v   = xs[dj] * wsv[dj];
            const float sel = (w < ws[dj]) ? 1.0f : 0.0f;
            accA[dj] = fmaf(v, sel, accA[dj]);
            accB[dj] = fmaf(v, 1.0f - sel, accB[dj]);
        }
    }

    float* ob = out + b * NPATCH;
    #pragma unroll
    for (int dj = 0; dj < 4; ++dj) {
        unsafeAtomicAdd(&ob[p0[dj]], accA[dj]);          // global_atomic_add_f32
        if (ws[dj] < 14)
            unsafeAtomicAdd(&ob[p0[dj] + 1], accB[dj]);  // rare (1.7% of runs)
    }
}

extern "C" void kernel_launch(void* const* d_in, const int* in_sizes, int n_in,
                              void* d_out, int out_size, void* d_ws, size_t ws_size,
                              hipStream_t stream) {
    const float* x      = (const float*)d_in[0];
    const float* weight = (const float*)d_in[1];
    const float* bias   = (const float*)d_in[2];
    float* out          = (float*)d_out;
    float* wlay         = (float*)d_ws;      // 602112 bytes

    prep_kernel<<<784, 256, 0, stream>>>(weight, bias, wlay, out);
    run_kernel<<<2688, 256, 0, stream>>>(x, wlay, out);   // 10752 waves = 256 img * 42 tiles
}

// Round 8
// 37.783 us; speedup vs baseline: 5.3887x; 1.6274x over previous
//
#include <hip/hip_runtime.h>

// SimpleUnsharedPatchScorer — register-run reduction, per-image blocks, zero global atomics.
// t = i*9408 + j*588 + c*196 + h*14 + w  (i,j in [0,16), c in [0,3), h,w in [0,14))
// value at t: x[b, c, 16h+i, 16w+j];  out bin p = t/768.
// Round-7 post-mortem: 61.5us with ~3.1M device-scope atomics suspected as the residual.
// Now: 1 block = 1 image (896 thr = 14 waves, wave wv = stripe h over 3 channels).
// Per-wave private LDS bin row (ds_add_f32), block tree-reduce, plain store. No atomics,
// no bias-init kernel, no out pre-read.

#define NPATCH 196
#define NF4IMG 37632     // float4s per image = 150528/4
#define BSTR   197       // LDS bin row stride (gcd(197 mod 32 = 5, 32)=1 -> spread banks)

// prep: wlay[((c*14+h)*14+w)*256 + i*16 + j] = weight[i*9408 + j*588 + c*196 + h*14 + w]
__global__ __launch_bounds__(256) void prep_kernel(
    const float* __restrict__ weight,
    float* __restrict__ wlay)
{
    const int f = blockIdx.x * 256 + threadIdx.x;   // grid 588 -> f < 150528
    const int j    = f & 15;
    const int i    = (f >> 4) & 15;
    const int rest = f >> 8;             // (c*14+h)*14 + w
    const int w  = rest % 14;
    const int ch = rest / 14;
    const int h  = ch % 14;
    const int c  = ch / 14;
    wlay[f] = weight[i * 9408 + j * 588 + c * 196 + h * 14 + w];
}

__global__ __launch_bounds__(896) void run_kernel(
    const float* __restrict__ x,     // [256,3,224,224]
    const float* __restrict__ wlay,  // permuted weights (602112 floats)
    const float* __restrict__ bias,  // [196]
    float* __restrict__ out)         // [256,196]
{
    __shared__ float bins[14 * BSTR];
    const int tid  = threadIdx.x;
    const int b    = blockIdx.x;     // image
    const int wv   = tid >> 6;       // wave id = h stripe
    const int lane = tid & 63;
    const int i    = lane >> 2;
    const int j4   = lane & 3;       // j = 4*j4 + dj

    for (int k = tid; k < 14 * BSTR; k += 896) bins[k] = 0.0f;
    __syncthreads();

    const int h = wv;
    float* mybins = bins + wv * BSTR;

    for (int c = 0; c < 3; ++c) {
        const int tile = c * 14 + h;
        const float4* __restrict__ x4 = (const float4*)x + (size_t)b * NF4IMG
                                        + c * 12544 + (16 * h + i) * 56 + j4;
        const float4* __restrict__ w4 = (const float4*)wlay + tile * 896 + i * 4 + j4;

        int p0[4], ws_[4];
        #pragma unroll
        for (int dj = 0; dj < 4; ++dj) {
            const int jj = 4 * j4 + dj;
            const int t0 = i * 9408 + jj * 588 + c * 196 + h * 14;
            p0[dj]  = t0 / 768;
            ws_[dj] = 768 * (p0[dj] + 1) - t0;   // w >= ws_ -> bin p0+1 (never past 195: max t0%768==754)
        }

        float accA[4] = {0.f, 0.f, 0.f, 0.f};
        float accB[4] = {0.f, 0.f, 0.f, 0.f};
        #pragma unroll
        for (int w = 0; w < 14; ++w) {
            const float4 xv  = x4[4 * w];
            const float4 wv_ = w4[64 * w];
            const float xs[4]  = {xv.x, xv.y, xv.z, xv.w};
            const float wsv[4] = {wv_.x, wv_.y, wv_.z, wv_.w};
            #pragma unroll
            for (int dj = 0; dj < 4; ++dj) {
                const float v   = xs[dj] * wsv[dj];
                const float sel = (w < ws_[dj]) ? 1.0f : 0.0f;
                accA[dj] = fmaf(v, sel, accA[dj]);
                accB[dj] = fmaf(v, 1.0f - sel, accB[dj]);
            }
        }

        #pragma unroll
        for (int dj = 0; dj < 4; ++dj) {
            unsafeAtomicAdd(&mybins[p0[dj]], accA[dj]);          // ds_add_f32, per-wave row
            if (ws_[dj] < 14)
                unsafeAtomicAdd(&mybins[p0[dj] + 1], accB[dj]);  // rare split (~1.7%)
        }
    }
    __syncthreads();

    // 14-way tree sum + bias, plain coalesced store
    for (int p = tid; p < NPATCH; p += 896) {
        float s = 0.0f;
        #pragma unroll
        for (int k = 0; k < 14; ++k) s += bins[k * BSTR + p];
        out[b * NPATCH + p] = s + bias[p];
    }
}

extern "C" void kernel_launch(void* const* d_in, const int* in_sizes, int n_in,
                              void* d_out, int out_size, void* d_ws, size_t ws_size,
                              hipStream_t stream) {
    const float* x      = (const float*)d_in[0];
    const float* weight = (const float*)d_in[1];
    const float* bias   = (const float*)d_in[2];
    float* out          = (float*)d_out;
    float* wlay         = (float*)d_ws;      // 602112 bytes

    prep_kernel<<<588, 256, 0, stream>>>(weight, wlay);
    run_kernel<<<256, 896, 0, stream>>>(x, wlay, bias, out);
}

// Round 9
// 35.938 us; speedup vs baseline: 5.6654x; 1.0513x over previous
//
#include <hip/hip_runtime.h>

// SimpleUnsharedPatchScorer — register-run reduction, h-split blocks.
// t = i*9408 + j*588 + c*196 + h*14 + w  (i,j in [0,16), c in [0,3), h,w in [0,14))
// value at t: x[b, c, 16h+i, 16w+j];  out bin p = t/768.
// R8 post-mortem: 37.8us total = 24.5 x-floor + ~5 prep (scattered loads) + ~8 run/launch.
// R9: (1) prep reads weight coalesced float4 / scatters stores (no load stall) + bias-init out;
//     (2) run = 512 blocks x 448 thr (7 waves, half image) -> 2 blocks/CU, overlap tails;
//         combine via 100K global atomics (32x less than R7's 3.1M wall).

#define NPATCH 196
#define NF4IMG 37632     // float4s per image = 150528/4
#define BSTR   197       // LDS bin row stride

// prep: grid 196x256. bid<147: wlay permute (coalesced weight read, scattered store).
//       bid>=147: out[g] = bias[g%196] (coalesced float4 store).
__global__ __launch_bounds__(256) void prep_kernel(
    const float* __restrict__ weight,
    const float* __restrict__ bias,
    float* __restrict__ wlay,
    float* __restrict__ out)
{
    const int bid = blockIdx.x;
    if (bid < 147) {                          // 147*256*4 == 150528
        const int t4 = bid * 256 + threadIdx.x;
        const float4 wv = ((const float4*)weight)[t4];
        const float wt[4] = {wv.x, wv.y, wv.z, wv.w};
        #pragma unroll
        for (int u = 0; u < 4; ++u) {
            const int t    = 4 * t4 + u;
            const int i    = t / 9408;
            const int rem  = t - i * 9408;
            const int jj   = rem / 588;
            const int rem2 = rem - jj * 588;
            const int c    = rem2 / 196;
            const int rem3 = rem2 - c * 196;
            const int h    = rem3 / 14;
            const int w    = rem3 - h * 14;
            wlay[((c * 14 + h) * 14 + w) * 256 + i * 16 + jj] = wt[u];
        }
    } else {                                  // 49*256*4 == 50176 == 256*196
        const int g4 = (bid - 147) * 256 + threadIdx.x;
        const int g  = 4 * g4;
        float4 o;
        o.x = bias[(g + 0) % NPATCH];
        o.y = bias[(g + 1) % NPATCH];
        o.z = bias[(g + 2) % NPATCH];
        o.w = bias[(g + 3) % NPATCH];
        ((float4*)out)[g4] = o;
    }
}

__global__ __launch_bounds__(448) void run_kernel(
    const float* __restrict__ x,     // [256,3,224,224]
    const float* __restrict__ wlay,  // permuted weights (602112 floats)
    float* __restrict__ out)         // [256,196], bias pre-loaded
{
    __shared__ float bins[7 * BSTR];
    const int tid  = threadIdx.x;
    const int b    = blockIdx.x >> 1;         // image
    const int hh   = blockIdx.x & 1;          // h half
    const int wv   = tid >> 6;                // wave 0..6
    const int lane = tid & 63;
    const int i    = lane >> 2;
    const int j4   = lane & 3;                // j = 4*j4 + dj
    const int h    = hh * 7 + wv;

    for (int k = tid; k < 7 * BSTR; k += 448) bins[k] = 0.0f;
    __syncthreads();

    float* mybins = bins + wv * BSTR;

    #pragma unroll
    for (int c = 0; c < 3; ++c) {
        const int tile = c * 14 + h;
        const float4* __restrict__ x4 = (const float4*)x + (size_t)b * NF4IMG
                                        + c * 12544 + (16 * h + i) * 56 + j4;
        const float4* __restrict__ w4 = (const float4*)wlay + tile * 896 + i * 4 + j4;

        int p0[4], ws_[4];
        #pragma unroll
        for (int dj = 0; dj < 4; ++dj) {
            const int jj = 4 * j4 + dj;
            const int t0 = i * 9408 + jj * 588 + c * 196 + h * 14;
            p0[dj]  = t0 / 768;
            ws_[dj] = 768 * (p0[dj] + 1) - t0;   // w >= ws_ -> bin p0+1 (max t0%768=754 -> ws_=14, no split)
        }

        float accA[4] = {0.f, 0.f, 0.f, 0.f};
        float accB[4] = {0.f, 0.f, 0.f, 0.f};
        #pragma unroll
        for (int w = 0; w < 14; ++w) {
            const float4 xv  = x4[4 * w];
            const float4 wv_ = w4[64 * w];
            const float xs[4]  = {xv.x, xv.y, xv.z, xv.w};
            const float wsv[4] = {wv_.x, wv_.y, wv_.z, wv_.w};
            #pragma unroll
            for (int dj = 0; dj < 4; ++dj) {
                const float v   = xs[dj] * wsv[dj];
                const float sel = (w < ws_[dj]) ? 1.0f : 0.0f;
                accA[dj] = fmaf(v, sel, accA[dj]);
                accB[dj] = fmaf(v, 1.0f - sel, accB[dj]);
            }
        }

        #pragma unroll
        for (int dj = 0; dj < 4; ++dj) {
            unsafeAtomicAdd(&mybins[p0[dj]], accA[dj]);          // ds_add_f32, per-wave row
            if (ws_[dj] < 14)
                unsafeAtomicAdd(&mybins[p0[dj] + 1], accB[dj]);  // rare split (~1.7%)
        }
    }
    __syncthreads();

    // 7-way tree sum, then one device atomic per (block, p): 196*512 ~= 100K total
    for (int p = tid; p < NPATCH; p += 448) {
        float s = 0.0f;
        #pragma unroll
        for (int k = 0; k < 7; ++k) s += bins[k * BSTR + p];
        unsafeAtomicAdd(&out[b * NPATCH + p], s);
    }
}

extern "C" void kernel_launch(void* const* d_in, const int* in_sizes, int n_in,
                              void* d_out, int out_size, void* d_ws, size_t ws_size,
                              hipStream_t stream) {
    const float* x      = (const float*)d_in[0];
    const float* weight = (const float*)d_in[1];
    const float* bias   = (const float*)d_in[2];
    float* out          = (float*)d_out;
    float* wlay         = (float*)d_ws;      // 602112 bytes

    prep_kernel<<<196, 256, 0, stream>>>(weight, bias, wlay, out);
    run_kernel<<<512, 448, 0, stream>>>(x, wlay, out);
}